// Round 4
// baseline (221.458 us; speedup 1.0000x reference)
//
#include <hip/hip_runtime.h>

// CBFHalfspace: h(x)=b-Ax, A[:,0:2]=[[-1,0],[1,0],[0,-1],[0,1]], b=1.
// h affine, A column-sums zero => all Lie-derivative outputs are exactly 0.
// Per-row output (8 floats): [1+x0, 1-x0, 1+x1, 1-x1, 0, 0, 0, 0].
//
// Byte floor: 117.4 MB read (every 64B line of x holds >=2 needed x0/x1
// pairs -> fully compulsory) + 134.2 MB NT write = 251.7 MB ~= 40 us @6.3TB/s.
//
// Round-4 evidence: kernel left the rocprof top-5 (<80 us, was 78.9), dur_us
// 230->219. NT loads killed the poison-dirty-L3 eviction traffic. Remaining
// structural cost: the block-wide __syncthreads() made all 4 waves wait for
// the slowest wave's staging loads before any store could issue.
//
// Round-5 structure: WAVE-PRIVATE staging, no barrier at all.
//   - Each 64-lane wave owns 256 rows: 256*7 floats = 448 float4 = exactly
//     7 unit-stride NT float4 loads per lane into its own LDS chunk.
//   - DS ops from one wave complete in order, and each wave reads only the
//     LDS region it wrote itself -> no __syncthreads needed; the compiler's
//     own lgkmcnt waits cover the intra-wave write->read dependency.
//   - Waves proceed independently: one wave's store phase overlaps sibling
//     waves' load latency instead of rendezvousing 4096 times.
//   - LDS reads at stride 7 floats, 32 even lanes read 32 consecutive rows:
//     bank = 7r mod 32, gcd(7,32)=1 -> conflict-free.
//   - NT stores, unit-stride float4, full 64B lines (even slot = h, odd = 0).
// 28 KB LDS/block -> 5 blocks/CU = 20 waves/CU; VGPR ~12. 4096 blocks.

typedef float v4f __attribute__((ext_vector_type(4)));

#define THREADS 256
#define RPW     256                      // rows per wave
#define RPB     (RPW * 4)                // 1024 rows per block (4 waves)
#define WXF4    (RPW * 7 / 4)            // 448 float4 of x per wave
#define WOF4    (RPW * 2)                // 512 float4 of out per wave

__global__ __launch_bounds__(256) void CBFHalfspace_68917045231689_kernel(
        const v4f* __restrict__ x4, v4f* __restrict__ out4) {
    __shared__ float xs[RPB * 7];        // 28672 B
    v4f* xs4 = (v4f*)xs;

    const int t    = threadIdx.x;
    const int w    = t >> 6;             // wave id 0..3
    const int lane = t & 63;

    // ---- stage this wave's 256 rows (7168 B) into its private LDS chunk ----
    const int    wf4   = w * WXF4;                         // LDS f4 offset
    const size_t xbase = (size_t)blockIdx.x * (4 * WXF4) + wf4;
#pragma unroll
    for (int i = 0; i < 7; ++i) {
        const int idx = lane + 64 * i;                     // unit-stride per instr
        xs4[wf4 + idx] = __builtin_nontemporal_load(&x4[xbase + idx]);
    }
    // no __syncthreads(): each wave only reads its own chunk; DS is in-order
    // per wave and lgkmcnt waits are inserted by the compiler.

    // ---- emit output: wave owns 512 consecutive float4 slots ----
    const float* xw    = xs + w * (RPW * 7);
    const v4f    z     = (v4f){0.0f, 0.0f, 0.0f, 0.0f};
    const size_t obase = (size_t)blockIdx.x * (4 * WOF4) + (size_t)w * WOF4;
#pragma unroll
    for (int i = 0; i < 8; ++i) {
        const int s = lane + 64 * i;     // parity(s) == parity(lane)
        v4f v = z;
        if (!(s & 1)) {
            const int   r  = s >> 1;     // row within wave chunk, 0..255
            const float x0 = xw[r * 7 + 0];
            const float x1 = xw[r * 7 + 1];
            v = (v4f){1.0f + x0, 1.0f - x0, 1.0f + x1, 1.0f - x1};
        }
        __builtin_nontemporal_store(v, &out4[obase + s]);
    }
}

extern "C" void kernel_launch(void* const* d_in, const int* in_sizes, int n_in,
                              void* d_out, int out_size, void* d_ws, size_t ws_size,
                              hipStream_t stream) {
    const v4f* x4 = (const v4f*)d_in[0]; // B*7 floats, B*7 % 4 == 0, 256B-aligned
    // d_in[1] (f) and d_in[2] (g) are mathematically irrelevant: grad(sum h)=0.
    v4f* out4 = (v4f*)d_out;

    const int rows = in_sizes[0] / 7;    // in_sizes[0] = element count = B*7
    const int grid = rows / RPB;         // 4096 blocks; rows % 1024 == 0
    CBFHalfspace_68917045231689_kernel<<<grid, THREADS, 0, stream>>>(x4, out4);
}